// Round 1
// baseline (1625.205 us; speedup 1.0000x reference)
//
#include <hip/hip_runtime.h>
#include <hip/hip_bf16.h>
#include <stdint.h>

#define IN_F   4096
#define OUT_F  11008
#define GS     128
#define M_TOT  8192   // BATCH*SEQ = 4*2048

#define BM 128
#define BN 128
#define BK 32

typedef __attribute__((ext_vector_type(8))) short          short8;
typedef __attribute__((ext_vector_type(8))) unsigned short ushort8;
typedef __attribute__((ext_vector_type(4))) float          f32x4;

// round-to-nearest-even fp32 -> bf16
static __device__ __forceinline__ unsigned short f2bf(float f) {
    union { float f; uint32_t u; } v; v.f = f;
    return (unsigned short)((v.u + 0x7FFFu + ((v.u >> 16) & 1u)) >> 16);
}

// ---------------- 1: x fp32 -> bf16 ----------------
__global__ __launch_bounds__(256) void convert_x(const float* __restrict__ x,
                                                 unsigned short* __restrict__ xb) {
    int tid = blockIdx.x * 256 + threadIdx.x;   // one thread = 8 elements
    const float4* xp = ((const float4*)x) + (size_t)tid * 2;
    float4 a = xp[0], b = xp[1];
    ushort8 o;
    o[0] = f2bf(a.x); o[1] = f2bf(a.y); o[2] = f2bf(a.z); o[3] = f2bf(a.w);
    o[4] = f2bf(b.x); o[5] = f2bf(b.y); o[6] = f2bf(b.z); o[7] = f2bf(b.w);
    ((ushort8*)xb)[tid] = o;
}

// ---------------- 2: dequant to W^T bf16 [N, K] ----------------
__global__ __launch_bounds__(256) void dequant_w(const int*   __restrict__ qw,
                                                 const int*   __restrict__ qz,
                                                 const float* __restrict__ sc,
                                                 unsigned short* __restrict__ wt) {
    int tid = blockIdx.x * 256 + threadIdx.x;     // over N * (IN_F/8)
    int k8 = tid & (IN_F / 8 - 1);                // 0..511
    int n  = tid >> 9;                            // 0..11007
    int g  = k8 >> 4;                             // (k8*8)/GS
    int q  = qw[(size_t)k8 * OUT_F + n];
    int zq = qz[(size_t)g * (OUT_F / 8) + (n >> 3)];
    int z  = ((zq >> ((n & 7) * 4)) & 0xF) + 1;
    float s = sc[(size_t)g * OUT_F + n];
    ushort8 o;
#pragma unroll
    for (int j = 0; j < 8; ++j) {
        int w = (q >> (4 * j)) & 0xF;
        o[j] = f2bf((float)(w - z) * s);
    }
    ((ushort8*)wt)[tid] = o;                      // wt[n*IN_F + k8*8 .. +8]
}

// ---------------- 3: bf16 GEMM, C = A * B^T (m97 structure) ----------------
__global__ __launch_bounds__(256) void gemm_bt(const unsigned short* __restrict__ A,
                                               const unsigned short* __restrict__ B,
                                               float* __restrict__ C) {
    __shared__ unsigned short lA[BM * BK];   // 8 KB
    __shared__ unsigned short lB[BN * BK];   // 8 KB

    const int tid  = threadIdx.x;
    const int lane = tid & 63;
    const int wave = tid >> 6;
    const int m0 = blockIdx.x * BM;
    const int n0 = blockIdx.y * BN;
    const int wm0 = (wave & 1) * 64;
    const int wn0 = (wave >> 1) * 64;

    f32x4 acc[4][4] = {};

    const int ar = lane >> 2;          // row within 16-row slab
    const int ac = (lane & 3) * 8;     // col element
    const unsigned short* gA = A + (size_t)(m0 + wave * 16 + ar) * IN_F + ac;
    const unsigned short* gB = B + (size_t)(n0 + wave * 16 + ar) * IN_F + ac;

    const int fr = lane & 15;          // fragment row (m or n)
    const int fk = (lane >> 4) * 8;    // fragment k offset

    for (int k0 = 0; k0 < IN_F; k0 += BK) {
        __syncthreads();
#pragma unroll
        for (int i = 0; i < 2; ++i) {
            __builtin_amdgcn_global_load_lds(
                (const __attribute__((address_space(1))) void*)(gA + (size_t)i * 64 * IN_F + k0),
                (__attribute__((address_space(3))) void*)&lA[(i * 64 + wave * 16) * BK],
                16, 0, 0);
            __builtin_amdgcn_global_load_lds(
                (const __attribute__((address_space(1))) void*)(gB + (size_t)i * 64 * IN_F + k0),
                (__attribute__((address_space(3))) void*)&lB[(i * 64 + wave * 16) * BK],
                16, 0, 0);
        }
        __syncthreads();

        short8 aF[4], bF[4];
#pragma unroll
        for (int t = 0; t < 4; ++t)
            aF[t] = *(const short8*)&lA[(wm0 + t * 16 + fr) * BK + fk];
#pragma unroll
        for (int t = 0; t < 4; ++t)
            bF[t] = *(const short8*)&lB[(wn0 + t * 16 + fr) * BK + fk];

#pragma unroll
        for (int i = 0; i < 4; ++i)
#pragma unroll
            for (int j = 0; j < 4; ++j)
                acc[i][j] = __builtin_amdgcn_mfma_f32_16x16x32_bf16(aF[i], bF[j], acc[i][j], 0, 0, 0);
    }

    // epilogue: C/D layout col=lane&15, row=(lane>>4)*4+r  [measured m89]
    const int col  = lane & 15;
    const int row4 = (lane >> 4) * 4;
#pragma unroll
    for (int i = 0; i < 4; ++i)
#pragma unroll
        for (int j = 0; j < 4; ++j)
#pragma unroll
            for (int r = 0; r < 4; ++r)
                C[(size_t)(m0 + wm0 + i * 16 + row4 + r) * OUT_F + (n0 + wn0 + j * 16 + col)] =
                    acc[i][j][r];
}

// ---------------- fallback (only if ws too small): fused naive fp32 ----------------
__global__ __launch_bounds__(256) void fallback_k(const float* __restrict__ x,
                                                  const int*   __restrict__ qw,
                                                  const int*   __restrict__ qz,
                                                  const float* __restrict__ sc,
                                                  float* __restrict__ out) {
    size_t tid = (size_t)blockIdx.x * 256 + threadIdx.x;
    if (tid >= (size_t)M_TOT * OUT_F) return;
    int n = (int)(tid % OUT_F);
    size_t m = tid / OUT_F;
    float acc = 0.f;
    for (int k8 = 0; k8 < IN_F / 8; ++k8) {
        int q = qw[(size_t)k8 * OUT_F + n];
        int g = k8 >> 4;
        int z = ((qz[(size_t)g * (OUT_F / 8) + (n >> 3)] >> ((n & 7) * 4)) & 0xF) + 1;
        float s = sc[(size_t)g * OUT_F + n];
#pragma unroll
        for (int j = 0; j < 8; ++j) {
            float w = (float)(((q >> (4 * j)) & 0xF) - z) * s;
            acc += x[m * IN_F + k8 * 8 + j] * w;
        }
    }
    out[tid] = acc;
}

extern "C" void kernel_launch(void* const* d_in, const int* in_sizes, int n_in,
                              void* d_out, int out_size, void* d_ws, size_t ws_size,
                              hipStream_t stream) {
    const float* x  = (const float*)d_in[0];
    const int*   qw = (const int*)d_in[1];
    const int*   qz = (const int*)d_in[2];
    const float* sc = (const float*)d_in[3];
    float* out = (float*)d_out;

    const size_t needA = (size_t)M_TOT * IN_F * 2;   // 67 MB bf16 x
    const size_t needB = (size_t)OUT_F * IN_F * 2;   // 90 MB bf16 W^T

    if (ws_size >= needA + needB) {
        unsigned short* xb = (unsigned short*)d_ws;
        unsigned short* wt = (unsigned short*)((char*)d_ws + needA);
        hipLaunchKernelGGL(convert_x, dim3(M_TOT * (IN_F / 8) / 256), dim3(256), 0, stream, x, xb);
        hipLaunchKernelGGL(dequant_w, dim3(OUT_F * (IN_F / 8) / 256), dim3(256), 0, stream,
                           qw, qz, sc, wt);
        hipLaunchKernelGGL(gemm_bt, dim3(M_TOT / BM, OUT_F / BN), dim3(256), 0, stream,
                           xb, wt, out);
    } else {
        size_t total = (size_t)M_TOT * OUT_F;
        hipLaunchKernelGGL(fallback_k, dim3((unsigned)((total + 255) / 256)), dim3(256), 0, stream,
                           x, qw, qz, sc, out);
    }
}